// Round 1
// baseline (80.092 us; speedup 1.0000x reference)
//
#include <hip/hip_runtime.h>

// Problem constants (match reference)
#define BS 16
#define Q  1000
#define NC 80
#define T  100
#define NI 8

#define ALPHA   0.25f
#define W_CLASS 2.0f
#define W_BBOX  5.0f
#define W_GIOU  2.0f

// One block per (b, i) query. Lanes 0..T-1 compute C_diag[b,i,j];
// lanes T..T+NI-1 compute ioa_diag[b,i,j-T]. Block = 128 (2 waves).
__global__ __launch_bounds__(128) void matcher_kernel(
    const float* __restrict__ pred_logits,   // (BS,Q,NC)
    const float* __restrict__ pred_boxes,    // (BS,Q,4)
    const float* __restrict__ tgt_bbox,      // (BS*T,4)
    const float* __restrict__ ign_bbox,      // (BS*NI,4)
    const float* __restrict__ img_sz,        // (BS,4)
    const float* __restrict__ img_sz_tgt,    // (BS*T,4)
    const int*   __restrict__ tgt_ids,       // (BS*T,)
    float* __restrict__ out)                 // C_diag (BS*Q*T) ++ ioa_diag (BS*Q*NI)
{
    const int n   = blockIdx.x;      // b*Q + i
    const int b   = n / Q;
    const int tid = threadIdx.x;

    // Per-query data (same for all lanes; broadcast via scalar cache/L1)
    const float4 pb  = *(const float4*)(pred_boxes + (size_t)n * 4);
    const float4 isz = *(const float4*)(img_sz     + (size_t)b * 4);
    const float area_p = (pb.z - pb.x) * (pb.w - pb.y);
    const float obx = pb.x / isz.x;
    const float oby = pb.y / isz.y;
    const float obz = pb.z / isz.z;
    const float obw = pb.w / isz.w;

    if (tid < T) {
        const int j = tid;
        const int r = b * T + j;
        const float4 tb  = *(const float4*)(tgt_bbox   + (size_t)r * 4);
        const float4 tsz = *(const float4*)(img_sz_tgt + (size_t)r * 4);

        // cost_bbox: L1 on normalized boxes
        const float cb = fabsf(obx - tb.x / tsz.x)
                       + fabsf(oby - tb.y / tsz.y)
                       + fabsf(obz - tb.z / tsz.z)
                       + fabsf(obw - tb.w / tsz.w);

        // cost_class: focal on gathered logit
        const int   cls   = tgt_ids[r];
        const float logit = pred_logits[(size_t)n * NC + cls];
        const float p     = 1.0f / (1.0f + expf(-logit));
        const float pos   =  ALPHA        * (1.0f - p) * (1.0f - p) * (-logf(p + 1e-8f));
        const float neg   = (1.0f - ALPHA) * p * p                   * (-logf(1.0f - p + 1e-8f));
        const float cost_class = pos - neg;

        // GIoU
        const float ltx = fmaxf(pb.x, tb.x), lty = fmaxf(pb.y, tb.y);
        const float rbx = fminf(pb.z, tb.z), rby = fminf(pb.w, tb.w);
        const float iw  = fmaxf(rbx - ltx, 0.0f), ih = fmaxf(rby - lty, 0.0f);
        const float inter = iw * ih;
        const float area_t = (tb.z - tb.x) * (tb.w - tb.y);
        const float uni  = area_p + area_t - inter;
        const float iou  = inter / uni;
        const float eltx = fminf(pb.x, tb.x), elty = fminf(pb.y, tb.y);
        const float erbx = fmaxf(pb.z, tb.z), erby = fmaxf(pb.w, tb.w);
        const float ew   = fmaxf(erbx - eltx, 0.0f), eh = fmaxf(erby - elty, 0.0f);
        const float enc  = ew * eh;
        const float giou = iou - (enc - uni) / enc;

        out[(size_t)n * T + j] = W_BBOX * cb + W_CLASS * cost_class + W_GIOU * (-giou);
    } else if (tid < T + NI) {
        const int j = tid - T;
        const int r = b * NI + j;
        const float4 ib = *(const float4*)(ign_bbox + (size_t)r * 4);
        const float ltx = fmaxf(pb.x, ib.x), lty = fmaxf(pb.y, ib.y);
        const float rbx = fminf(pb.z, ib.z), rby = fminf(pb.w, ib.w);
        const float iw  = fmaxf(rbx - ltx, 0.0f), ih = fmaxf(rby - lty, 0.0f);
        const float inter = iw * ih;
        out[(size_t)BS * Q * T + (size_t)n * NI + j] = inter / area_p;
    }
}

extern "C" void kernel_launch(void* const* d_in, const int* in_sizes, int n_in,
                              void* d_out, int out_size, void* d_ws, size_t ws_size,
                              hipStream_t stream) {
    const float* pred_logits = (const float*)d_in[0];
    const float* pred_boxes  = (const float*)d_in[1];
    const float* tgt_bbox    = (const float*)d_in[2];
    const float* ign_bbox    = (const float*)d_in[3];
    const float* img_sz      = (const float*)d_in[4];
    const float* img_sz_tgt  = (const float*)d_in[5];
    const int*   tgt_ids     = (const int*)d_in[6];
    float* out = (float*)d_out;

    matcher_kernel<<<BS * Q, 128, 0, stream>>>(
        pred_logits, pred_boxes, tgt_bbox, ign_bbox, img_sz, img_sz_tgt, tgt_ids, out);
}

// Round 2
// 73.492 us; speedup vs baseline: 1.0898x; 1.0898x over previous
//
#include <hip/hip_runtime.h>

// Problem constants (match reference)
constexpr int BS = 16, Q = 1000, NC = 80, T = 100, NI = 8;
constexpr int CTOT = BS * Q * T;        // 1,600,000 C_diag entries
constexpr int ITOT = BS * Q * NI;       //   128,000 ioa_diag entries
constexpr int TOT  = CTOT + ITOT;       // 1,728,000 == out_size

#define ALPHA   0.25f
#define W_CLASS 2.0f
#define W_BBOX  5.0f
#define W_GIOU  2.0f

__device__ __forceinline__ float rcp(float x)  { return __builtin_amdgcn_rcpf(x); }
__device__ __forceinline__ float ex2(float x)  { return __builtin_amdgcn_exp2f(x); }
__device__ __forceinline__ float lg2(float x)  { return __builtin_amdgcn_logf(x); }
// ln(x) = log2(x) * ln(2);  sigmoid(x) = 1/(1+2^(-x*log2(e)))
#define LOG2E 1.44269504088896f
#define LN2   0.69314718055995f

// Flat one-thread-per-output. out[idx] for idx < CTOT is C_diag[(n=idx/T), j=idx%T];
// for idx >= CTOT it is ioa_diag[(n=(idx-CTOT)/NI), j=(idx-CTOT)%NI].
// This matches the harness's concatenated output layout exactly -> coalesced stores.
__global__ __launch_bounds__(256) void matcher_kernel(
    const float* __restrict__ pred_logits,   // (BS,Q,NC)
    const float* __restrict__ pred_boxes,    // (BS,Q,4)
    const float* __restrict__ tgt_bbox,      // (BS*T,4)
    const float* __restrict__ ign_bbox,      // (BS*NI,4)
    const float* __restrict__ img_sz,        // (BS,4)
    const float* __restrict__ img_sz_tgt,    // (BS*T,4)
    const int*   __restrict__ tgt_ids,       // (BS*T,)
    float* __restrict__ out)
{
    const int idx = blockIdx.x * 256 + threadIdx.x;
    if (idx >= TOT) return;

    if (idx < CTOT) {
        const int n = idx / T;          // compiler magic-mul
        const int j = idx - n * T;
        const int b = n / Q;
        const int r = b * T + j;

        const float4 pb  = *(const float4*)(pred_boxes  + (size_t)n * 4);
        const float4 tb  = *(const float4*)(tgt_bbox    + (size_t)r * 4);
        const float4 isz = *(const float4*)(img_sz      + (size_t)b * 4);
        const float4 tsz = *(const float4*)(img_sz_tgt  + (size_t)r * 4);

        // cost_bbox: L1 on normalized boxes (rcp ~1ulp; threshold is 0.44)
        const float cb = fabsf(pb.x * rcp(isz.x) - tb.x * rcp(tsz.x))
                       + fabsf(pb.y * rcp(isz.y) - tb.y * rcp(tsz.y))
                       + fabsf(pb.z * rcp(isz.z) - tb.z * rcp(tsz.z))
                       + fabsf(pb.w * rcp(isz.w) - tb.w * rcp(tsz.w));

        // cost_class: focal on gathered logit (hardware exp/log)
        const int   cls   = tgt_ids[r];
        const float logit = pred_logits[(size_t)n * NC + cls];
        const float p     = rcp(1.0f + ex2(-logit * LOG2E));
        const float omp   = 1.0f - p;
        const float pos   =  ALPHA         * omp * omp * (-(lg2(p   + 1e-8f) * LN2));
        const float neg   = (1.0f - ALPHA) * p   * p   * (-(lg2(omp + 1e-8f) * LN2));
        const float cost_class = pos - neg;

        // GIoU
        const float area_p = (pb.z - pb.x) * (pb.w - pb.y);
        const float area_t = (tb.z - tb.x) * (tb.w - tb.y);
        const float iw  = fmaxf(fminf(pb.z, tb.z) - fmaxf(pb.x, tb.x), 0.0f);
        const float ih  = fmaxf(fminf(pb.w, tb.w) - fmaxf(pb.y, tb.y), 0.0f);
        const float inter = iw * ih;
        const float uni   = area_p + area_t - inter;
        const float ew  = fmaxf(fmaxf(pb.z, tb.z) - fminf(pb.x, tb.x), 0.0f);
        const float eh  = fmaxf(fmaxf(pb.w, tb.w) - fminf(pb.y, tb.y), 0.0f);
        const float enc = ew * eh;
        const float giou = inter * rcp(uni) - (enc - uni) * rcp(enc);

        out[idx] = W_BBOX * cb + W_CLASS * cost_class - W_GIOU * giou;
    } else {
        const int k = idx - CTOT;
        const int n = k >> 3;           // / NI
        const int j = k & (NI - 1);
        const int b = n / Q;
        const int r = b * NI + j;

        const float4 pb = *(const float4*)(pred_boxes + (size_t)n * 4);
        const float4 ib = *(const float4*)(ign_bbox   + (size_t)r * 4);
        const float area_p = (pb.z - pb.x) * (pb.w - pb.y);
        const float iw  = fmaxf(fminf(pb.z, ib.z) - fmaxf(pb.x, ib.x), 0.0f);
        const float ih  = fmaxf(fminf(pb.w, ib.w) - fmaxf(pb.y, ib.y), 0.0f);
        out[idx] = iw * ih * rcp(area_p);
    }
}

extern "C" void kernel_launch(void* const* d_in, const int* in_sizes, int n_in,
                              void* d_out, int out_size, void* d_ws, size_t ws_size,
                              hipStream_t stream) {
    const float* pred_logits = (const float*)d_in[0];
    const float* pred_boxes  = (const float*)d_in[1];
    const float* tgt_bbox    = (const float*)d_in[2];
    const float* ign_bbox    = (const float*)d_in[3];
    const float* img_sz      = (const float*)d_in[4];
    const float* img_sz_tgt  = (const float*)d_in[5];
    const int*   tgt_ids     = (const int*)d_in[6];
    float* out = (float*)d_out;

    const int blocks = (TOT + 255) / 256;   // 6750
    matcher_kernel<<<blocks, 256, 0, stream>>>(
        pred_logits, pred_boxes, tgt_bbox, ign_bbox, img_sz, img_sz_tgt, tgt_ids, out);
}